// Round 1
// 550.202 us; speedup vs baseline: 1.0395x; 1.0395x over previous
//
#include <hip/hip_runtime.h>
#include <hip/hip_bf16.h>
#include <math.h>

typedef __attribute__((ext_vector_type(8))) short short8;
typedef __attribute__((ext_vector_type(4))) float floatx4;
typedef unsigned short u16;
typedef unsigned int u32;

// ---------- bf16 helpers ----------
__device__ __forceinline__ u16 f2b(float f) {
  union { float f; u32 i; } v; v.f = f;
  u32 i = v.i;
  return (u16)((i + 0x7fffu + ((i >> 16) & 1u)) >> 16);  // RNE
}

// ---------- async global->LDS (16B/lane) ----------
#define GLD16(gp, lp)                                                          \
  __builtin_amdgcn_global_load_lds(                                            \
      (__attribute__((address_space(1))) u32*)(gp),                            \
      (__attribute__((address_space(3))) u32*)(lp), 16, 0, 0)

// ---------- constants ----------
#define T_TOK 4096
#define DDIM 1024
#define FDIM 2048
#define NEXP 8
// merged capacity: routed padded-to-256 (<=9984 worst case) + 4096 shared
#define CAP_ROWS 14080
#define CAP_MBLK 55   // CAP_ROWS/256

// ---------- fallback: ws too small -> sentinel 1e6 (distinguishable) ----------
__global__ void fallback_k(float* out, int n) {
  int i = blockIdx.x * 256 + threadIdx.x;
  if (i < n) out[i] = 1.0e6f;
}

// ---------- init ----------
__global__ void init_k(int* counts, int* rowtok) {
  int i = blockIdx.x * 256 + threadIdx.x;
  if (i < CAP_ROWS) rowtok[i] = -1;
  if (i < NEXP) counts[i] = 0;
}

// ---------- zero the output (combine becomes pure atomicAdd) ----------
__global__ void zero_k(float* p) {
  int i = (blockIdx.x * 256 + threadIdx.x) * 4;
  *(float4*)(p + i) = make_float4(0.f, 0.f, 0.f, 0.f);
}

// ---------- convert x f32 -> bf16 ----------
__global__ void cvt_k(const float* __restrict__ x, u16* __restrict__ xb) {
  int i = (blockIdx.x * 256 + threadIdx.x) * 4;
  float4 v = *(const float4*)(x + i);
  union { u16 h[4]; uint2 u; } o;
  o.h[0] = f2b(v.x); o.h[1] = f2b(v.y); o.h[2] = f2b(v.z); o.h[3] = f2b(v.w);
  *(uint2*)(xb + i) = o.u;
}

// ---------- router: LDS-staged Wg (transposed), 16 tokens/block, f32 math ----------
__global__ __launch_bounds__(256) void router_k(const float* __restrict__ x,
                                                const float* __restrict__ Wg,
                                                int* topi, float* topw, int* counts) {
  __shared__ float wgl[NEXP * DDIM];  // 32 KB, [e][d]
  const int tid = threadIdx.x;
#pragma unroll
  for (int k = 0; k < (NEXP * DDIM) / 256; k++) {
    int i = tid + k * 256;          // coalesced flat read of Wg [d][e]
    wgl[(i & 7) * DDIM + (i >> 3)] = Wg[i];
  }
  __syncthreads();
  const int wave = tid >> 6, lane = tid & 63;
  for (int j = 0; j < 4; j++) {
    int t = blockIdx.x * 16 + wave * 4 + j;
    const float* xr = x + (size_t)t * DDIM;
    float p[NEXP];
#pragma unroll
    for (int e = 0; e < NEXP; e++) p[e] = 0.f;
#pragma unroll
    for (int i = 0; i < 4; i++) {
      int d0 = i * 256 + lane * 4;
      float4 xv = *(const float4*)(xr + d0);
#pragma unroll
      for (int e = 0; e < NEXP; e++) {
        float4 wv = *(const float4*)(wgl + e * DDIM + d0);
        p[e] += xv.x * wv.x + xv.y * wv.y + xv.z * wv.z + xv.w * wv.w;
      }
    }
#pragma unroll
    for (int off = 32; off > 0; off >>= 1)
#pragma unroll
      for (int e = 0; e < NEXP; e++) p[e] += __shfl_xor(p[e], off);
    if (lane == 0) {
      int i0 = 0; float l0 = p[0];
      for (int e = 1; e < NEXP; e++) if (p[e] > l0) { l0 = p[e]; i0 = e; }
      int i1 = (i0 == 0) ? 1 : 0; float l1 = p[i1];
      for (int e = 0; e < NEXP; e++) if (e != i0 && p[e] > l1) { l1 = p[e]; i1 = e; }
      float e1 = expf(l1 - l0);
      float s = 1.0f + e1;
      topi[t * 2] = i0; topi[t * 2 + 1] = i1;
      topw[t * 2] = 1.0f / s; topw[t * 2 + 1] = e1 / s;
      atomicAdd(&counts[i0], 1); atomicAdd(&counts[i1], 1);
    }
  }
}

// ---------- scan: serial 9-segment prefix (8 routed pad-256 + shared 4096) ----------
// meta[0] = total rows, meta[1] = shared segment base
__global__ void scan_k(const int* counts, int* cursor, int* blk_e, int* meta) {
  __shared__ int soff[NEXP + 1];
  const int tid = threadIdx.x;  // 64 threads
  if (tid == 0) {
    int off = 0;
    for (int e = 0; e < NEXP; e++) {
      soff[e] = off;
      int c = counts[e]; if (c < 0) c = 0; if (c > 4096) c = 4096;
      off += ((c + 255) >> 8) << 8;
    }
    if (off > CAP_ROWS - 4096) off = CAP_ROWS - 4096;
    soff[NEXP] = off;
    meta[1] = off;
    meta[0] = off + 4096;
  }
  __syncthreads();
  if (tid < NEXP) cursor[tid] = soff[tid];
  if (tid < CAP_MBLK) {
    int r = tid << 8;
    int e;
    if (r >= soff[NEXP]) e = NEXP;   // shared expert segment
    else {
      e = 0;
      for (int k = 0; k < NEXP; k++) if (r >= soff[k + 1]) e = k + 1;
      if (e > NEXP - 1) e = NEXP - 1;
    }
    blk_e[tid] = e;
  }
}

// ---------- assign: routed slots + shared segment fill ----------
__global__ void assign_k(const int* topi, const float* topw, int* cursor,
                         const int* meta, int* rowtok, float* rww) {
  int i = blockIdx.x * 256 + threadIdx.x;  // 12288 threads
  if (i < T_TOK * 2) {
    int e = topi[i]; if (e < 0) e = 0; if (e >= NEXP) e = NEXP - 1;
    int r = atomicAdd(&cursor[e], 1);
    if (r < 0) r = 0; if (r >= CAP_ROWS) r = CAP_ROWS - 1;
    rowtok[r] = i >> 1;
    rww[r] = topw[i];
  } else {
    int t = i - T_TOK * 2;            // 0..4095
    int r = meta[1] + t;
    if (r >= CAP_ROWS) r = CAP_ROWS - 1;
    rowtok[r] = t;
    rww[r] = 1.0f;
  }
}

// ---------- transpose+convert: f32 [R][C] -> bf16 [C][R], batched ----------
__global__ void transpose_cvt_k(const float* __restrict__ src, u16* __restrict__ dst,
                                int R, int C) {
  __shared__ float tile[32][33];
  size_t base = (size_t)blockIdx.z * R * C;
  int c0 = blockIdx.x * 32, r0 = blockIdx.y * 32;
#pragma unroll
  for (int i = 0; i < 4; i++)
    tile[threadIdx.y + i * 8][threadIdx.x] =
        src[base + (size_t)(r0 + threadIdx.y + i * 8) * C + c0 + threadIdx.x];
  __syncthreads();
#pragma unroll
  for (int i = 0; i < 4; i++)
    dst[base + (size_t)(c0 + threadIdx.y + i * 8) * R + r0 + threadIdx.x] =
        f2b(tile[threadIdx.x][threadIdx.y + i * 8]);
}

// ---------- 256x256 BK=64 8-wave phase-interleaved grouped GEMM ----------
// Techniques (guide T1..T5): XCD-chunked block swizzle, LDS XOR swizzle via
// pre-swizzled global_load_lds source, counted vmcnt(8) (never drain in loop),
// per-phase barriers + setprio around MFMA clusters.
// MODE 0: gelu -> bf16 store to C16
// MODE 2: atomic f32: Cf[rowtok[row]*N+col] += rww[row]*v  (skip rowtok<0)
template <int MODE>
__global__ __launch_bounds__(512, 2) void gemm256(
    const u16* __restrict__ A, const u16* __restrict__ Bt,
    u16* __restrict__ C16, float* __restrict__ Cf,
    int N, int K, const int* __restrict__ blk_e, const int* __restrict__ meta,
    size_t bstride, const int* __restrict__ gatherA,
    const int* __restrict__ rowtok, const float* __restrict__ rww) {
  // ---- bijective XCD-chunked swizzle of flattened block id (m204 formula) ----
  const int nwg = gridDim.x * gridDim.y;
  const int bid = blockIdx.y * gridDim.x + blockIdx.x;
  const int q = nwg >> 3, r8 = nwg & 7;
  const int xcd = bid & 7, idx = bid >> 3;
  const int swz = (xcd < r8) ? xcd * (q + 1) + idx
                             : r8 * (q + 1) + (xcd - r8) * q + idx;
  const int bx = swz % gridDim.x, by = swz / gridDim.x;

  const int m0 = by * 256, n0 = bx * 256;
  if (m0 >= meta[0]) return;
  Bt += (size_t)blk_e[by] * bstride;

  __shared__ u16 lds[2][2][256 * 64];  // [dbuf][A/B][row*64+col], 128 KiB

  const int tid = threadIdx.x;
  const int wave = tid >> 6, lane = tid & 63;
  const int wm = wave >> 2, wn = wave & 3;   // 2 x 4 wave grid
  const int fr = lane & 15, hi = lane >> 4;

  // ---- staging sources: chunk c = i*512+tid covers physical 16B slot (r, c&7)
  // of the [256][64] tile; it must fetch LOGICAL slot (c&7)^(r&7)  (XOR swizzle,
  // applied on the global side because global_load_lds writes LDS linearly).
  const u16* asrc[4];
  const u16* bsrc[4];
#pragma unroll
  for (int i = 0; i < 4; i++) {
    int c = i * 512 + tid;
    int r = c >> 3;
    int sl = (c & 7) ^ (r & 7);
    int ga = m0 + r;
    if (gatherA) { int t2 = gatherA[ga]; ga = (t2 < 0 || t2 >= T_TOK) ? 0 : t2; }
    asrc[i] = A + (size_t)ga * K + sl * 8;
    bsrc[i] = Bt + (size_t)(n0 + r) * K + sl * 8;
  }

  auto STAGE = [&](int kt, int d) {
    const int k0 = kt << 6;
#pragma unroll
    for (int i = 0; i < 4; i++)
      GLD16(asrc[i] + k0, &lds[d][0][i * 4096 + wave * 512]);
#pragma unroll
    for (int i = 0; i < 4; i++)
      GLD16(bsrc[i] + k0, &lds[d][1][i * 4096 + wave * 512]);
  };

  // ---- per-lane ds_read offsets; r&7 == fr&7 for every fragment row, so the
  // swizzled slot is a per-(lane,k) constant and fragment addrs are base+imm.
  int co[2];
#pragma unroll
  for (int k = 0; k < 2; k++)
    co[k] = fr * 64 + (((k << 2) + hi) ^ (fr & 7)) * 8;
  const int sA = wm * 8192;   // wm*128 rows * 64
  const int sB = wn * 4096;   // wn*64  rows * 64

  floatx4 acc[8][4];
#pragma unroll
  for (int mi = 0; mi < 8; mi++)
#pragma unroll
    for (int ni = 0; ni < 4; ni++) acc[mi][ni] = (floatx4){0.f, 0.f, 0.f, 0.f};

  const int NT = K >> 6;
  STAGE(0, 0);
  for (int t = 0; t < NT; ++t) {
    const int cur = t & 1;
    if (t + 1 < NT) {
      STAGE(t + 1, cur ^ 1);
      // counted wait: 8 new loads stay in flight; the 8 oldest (this tile) done
      asm volatile("s_waitcnt vmcnt(8)" ::: "memory");
    } else {
      asm volatile("s_waitcnt vmcnt(0)" ::: "memory");
    }
    __builtin_amdgcn_s_barrier();
    const u16* At = &lds[cur][0][0];
    const u16* Bl = &lds[cur][1][0];
#pragma unroll
    for (int ph = 0; ph < 4; ph++) {
      const int mh = ph >> 1, nh = ph & 1;  // C-quadrant of the wave tile
      short8 aF[4][2], bF[2][2];
#pragma unroll
      for (int mi = 0; mi < 4; mi++)
#pragma unroll
        for (int k = 0; k < 2; k++)
          aF[mi][k] = *(const short8*)(At + sA + (mh * 4 + mi) * 1024 + co[k]);
#pragma unroll
      for (int ni = 0; ni < 2; ni++)
#pragma unroll
        for (int k = 0; k < 2; k++)
          bF[ni][k] = *(const short8*)(Bl + sB + (nh * 2 + ni) * 1024 + co[k]);
      __builtin_amdgcn_s_barrier();
      __builtin_amdgcn_s_setprio(1);
#pragma unroll
      for (int mi = 0; mi < 4; mi++)
#pragma unroll
        for (int ni = 0; ni < 2; ni++)
#pragma unroll
          for (int k = 0; k < 2; k++)
            acc[mh * 4 + mi][nh * 2 + ni] = __builtin_amdgcn_mfma_f32_16x16x32_bf16(
                aF[mi][k], bF[ni][k], acc[mh * 4 + mi][nh * 2 + ni], 0, 0, 0);
      __builtin_amdgcn_s_setprio(0);
      __builtin_amdgcn_s_barrier();
    }
  }

  // ---- epilogue: C/D layout col=lane&15, row=(lane>>4)*4+reg ----
#pragma unroll
  for (int mi = 0; mi < 8; mi++)
#pragma unroll
    for (int r = 0; r < 4; r++) {
      int row = m0 + wm * 128 + mi * 16 + hi * 4 + r;
      int tok = 0; float w = 0.f;
      if (MODE == 2) {
        tok = rowtok[row];
        if (tok >= 0) w = rww[row];
      }
#pragma unroll
      for (int ni = 0; ni < 4; ni++) {
        int col = n0 + wn * 64 + ni * 16 + fr;
        float v = acc[mi][ni][r];
        if (MODE == 0) {
          v = 0.5f * v * (1.0f + erff(v * 0.70710678118654752f));
          C16[(size_t)row * N + col] = f2b(v);
        } else {
          if (tok >= 0) atomicAdd(Cf + (size_t)tok * N + col, w * v);
        }
      }
    }
}

extern "C" void kernel_launch(void* const* d_in, const int* in_sizes, int n_in,
                              void* d_out, int out_size, void* d_ws, size_t ws_size,
                              hipStream_t stream) {
  const float* x  = (const float*)d_in[0];
  const float* Wg = (const float*)d_in[1];
  const float* Wu = (const float*)d_in[2];
  const float* Wd = (const float*)d_in[3];
  const float* W1 = (const float*)d_in[4];
  const float* W2 = (const float*)d_in[5];
  float* out = (float*)d_out;

  // ---- workspace layout (~104 MB; Wt reused up->down) ----
  char* ws = (char*)d_ws;
  size_t off = 0;
  auto alloc = [&](size_t b) -> void* {
    void* p = ws + off; off += (b + 255) & ~(size_t)255; return p;
  };
  int*   counts = (int*)alloc(NEXP * 4);
  int*   cursor = (int*)alloc(NEXP * 4);
  int*   meta   = (int*)alloc(2 * 4);
  int*   blk_e  = (int*)alloc(CAP_MBLK * 4);
  int*   topi   = (int*)alloc(T_TOK * 2 * 4);
  float* topw   = (float*)alloc(T_TOK * 2 * 4);
  int*   rowtok = (int*)alloc(CAP_ROWS * 4);
  float* rww    = (float*)alloc(CAP_ROWS * 4);
  u16*   Xb     = (u16*)alloc((size_t)T_TOK * DDIM * 2);                 // 8.4 MB
  u16*   Wt     = (u16*)alloc((size_t)(NEXP + 1) * FDIM * DDIM * 2);     // 37.7 MB
  u16*   Hrg    = (u16*)alloc((size_t)CAP_ROWS * FDIM * 2);              // 57.7 MB
  (void)n_in; (void)in_sizes; (void)out_size;

  if (ws_size < off) {
    fallback_k<<<(T_TOK * DDIM + 255) / 256, 256, 0, stream>>>(out, T_TOK * DDIM);
    return;
  }

  dim3 tb(32, 8);
  // ---- routing (f32 logits: selection must match reference) ----
  init_k<<<CAP_ROWS / 256, 256, 0, stream>>>(counts, rowtok);
  cvt_k<<<T_TOK * DDIM / 1024, 256, 0, stream>>>(x, Xb);
  router_k<<<T_TOK / 16, 256, 0, stream>>>(x, Wg, topi, topw, counts);
  scan_k<<<1, 64, 0, stream>>>(counts, cursor, blk_e, meta);
  assign_k<<<(T_TOK * 2 + T_TOK) / 256, 256, 0, stream>>>(topi, topw, cursor, meta,
                                                          rowtok, rww);
  zero_k<<<T_TOK * DDIM / 1024, 256, 0, stream>>>(out);
  // ---- phase up: Hrg = gelu(gather(x) @ Wu[e])  (expert 8 = shared W1) ----
  transpose_cvt_k<<<dim3(FDIM / 32, DDIM / 32, NEXP), tb, 0, stream>>>(Wu, Wt, DDIM, FDIM);
  transpose_cvt_k<<<dim3(FDIM / 32, DDIM / 32, 1), tb, 0, stream>>>(
      W1, Wt + (size_t)NEXP * FDIM * DDIM, DDIM, FDIM);
  gemm256<0><<<dim3(FDIM / 256, CAP_MBLK), 512, 0, stream>>>(
      Xb, Wt, Hrg, nullptr, FDIM, DDIM, blk_e, meta, (size_t)FDIM * DDIM,
      rowtok, nullptr, nullptr);
  // ---- phase down: out += rww * (Hrg @ Wd[e])  (expert 8 = shared W2, w=1) ----
  transpose_cvt_k<<<dim3(DDIM / 32, FDIM / 32, NEXP), tb, 0, stream>>>(Wd, Wt, FDIM, DDIM);
  transpose_cvt_k<<<dim3(DDIM / 32, FDIM / 32, 1), tb, 0, stream>>>(
      W2, Wt + (size_t)NEXP * DDIM * FDIM, FDIM, DDIM);
  gemm256<2><<<dim3(DDIM / 256, CAP_MBLK), 512, 0, stream>>>(
      Hrg, Wt, nullptr, out, DDIM, FDIM, blk_e, meta, (size_t)DDIM * FDIM,
      nullptr, rowtok, rww);
}

// Round 2
// 549.895 us; speedup vs baseline: 1.0401x; 1.0006x over previous
//
#include <hip/hip_runtime.h>
#include <hip/hip_bf16.h>
#include <math.h>

typedef __attribute__((ext_vector_type(8))) short short8;
typedef __attribute__((ext_vector_type(4))) float floatx4;
typedef unsigned short u16;
typedef unsigned int u32;

// ---------- bf16 helpers ----------
__device__ __forceinline__ u16 f2b(float f) {
  union { float f; u32 i; } v; v.f = f;
  u32 i = v.i;
  return (u16)((i + 0x7fffu + ((i >> 16) & 1u)) >> 16);  // RNE
}

// ---------- async global->LDS (16B/lane) ----------
#define GLD16(gp, lp)                                                          \
  __builtin_amdgcn_global_load_lds(                                            \
      (__attribute__((address_space(1))) u32*)(gp),                            \
      (__attribute__((address_space(3))) u32*)(lp), 16, 0, 0)

// ---------- constants ----------
#define T_TOK 4096
#define DDIM 1024
#define FDIM 2048
#define NEXP 8
// merged capacity: routed padded-to-256 (<=9984 worst case) + 4096 shared
#define CAP_ROWS 14080
#define CAP_MBLK 55   // CAP_ROWS/256

// ---------- fallback: ws too small -> sentinel 1e6 (distinguishable) ----------
__global__ void fallback_k(float* out, int n) {
  int i = blockIdx.x * 256 + threadIdx.x;
  if (i < n) out[i] = 1.0e6f;
}

// ---------- fused prep: counts/rowtok init + out zero + x f32->bf16 ----------
__global__ void prep_k(const float* __restrict__ x, u16* __restrict__ xb,
                       float* __restrict__ out, int* counts, int* rowtok) {
  int i = blockIdx.x * 256 + threadIdx.x;
  if (i < NEXP) counts[i] = 0;
  if (i < CAP_ROWS) rowtok[i] = -1;
  int j = i * 4;  // grid sized so j < T_TOK*DDIM always
  float4 v = *(const float4*)(x + j);
  union { u16 h[4]; uint2 u; } o;
  o.h[0] = f2b(v.x); o.h[1] = f2b(v.y); o.h[2] = f2b(v.z); o.h[3] = f2b(v.w);
  *(uint2*)(xb + j) = o.u;
  *(float4*)(out + j) = make_float4(0.f, 0.f, 0.f, 0.f);
}

// ---------- router: LDS-staged Wg (transposed), 16 tokens/block, f32 math ----------
__global__ __launch_bounds__(256) void router_k(const float* __restrict__ x,
                                                const float* __restrict__ Wg,
                                                int* topi, float* topw, int* counts) {
  __shared__ float wgl[NEXP * DDIM];  // 32 KB, [e][d]
  const int tid = threadIdx.x;
#pragma unroll
  for (int k = 0; k < (NEXP * DDIM) / 256; k++) {
    int i = tid + k * 256;          // coalesced flat read of Wg [d][e]
    wgl[(i & 7) * DDIM + (i >> 3)] = Wg[i];
  }
  __syncthreads();
  const int wave = tid >> 6, lane = tid & 63;
  for (int j = 0; j < 4; j++) {
    int t = blockIdx.x * 16 + wave * 4 + j;
    const float* xr = x + (size_t)t * DDIM;
    float p[NEXP];
#pragma unroll
    for (int e = 0; e < NEXP; e++) p[e] = 0.f;
#pragma unroll
    for (int i = 0; i < 4; i++) {
      int d0 = i * 256 + lane * 4;
      float4 xv = *(const float4*)(xr + d0);
#pragma unroll
      for (int e = 0; e < NEXP; e++) {
        float4 wv = *(const float4*)(wgl + e * DDIM + d0);
        p[e] += xv.x * wv.x + xv.y * wv.y + xv.z * wv.z + xv.w * wv.w;
      }
    }
#pragma unroll
    for (int off = 32; off > 0; off >>= 1)
#pragma unroll
      for (int e = 0; e < NEXP; e++) p[e] += __shfl_xor(p[e], off);
    if (lane == 0) {
      int i0 = 0; float l0 = p[0];
      for (int e = 1; e < NEXP; e++) if (p[e] > l0) { l0 = p[e]; i0 = e; }
      int i1 = (i0 == 0) ? 1 : 0; float l1 = p[i1];
      for (int e = 0; e < NEXP; e++) if (e != i0 && p[e] > l1) { l1 = p[e]; i1 = e; }
      float e1 = expf(l1 - l0);
      float s = 1.0f + e1;
      topi[t * 2] = i0; topi[t * 2 + 1] = i1;
      topw[t * 2] = 1.0f / s; topw[t * 2 + 1] = e1 / s;
      atomicAdd(&counts[i0], 1); atomicAdd(&counts[i1], 1);
    }
  }
}

// ---------- scan: serial 9-segment prefix (8 routed pad-256 + shared 4096) ----------
// meta[0] = total rows, meta[1] = shared segment base
__global__ void scan_k(const int* counts, int* cursor, int* blk_e, int* meta) {
  __shared__ int soff[NEXP + 1];
  const int tid = threadIdx.x;  // 64 threads
  if (tid == 0) {
    int off = 0;
    for (int e = 0; e < NEXP; e++) {
      soff[e] = off;
      int c = counts[e]; if (c < 0) c = 0; if (c > 4096) c = 4096;
      off += ((c + 255) >> 8) << 8;
    }
    if (off > CAP_ROWS - 4096) off = CAP_ROWS - 4096;
    soff[NEXP] = off;
    meta[1] = off;
    meta[0] = off + 4096;
  }
  __syncthreads();
  if (tid < NEXP) cursor[tid] = soff[tid];
  if (tid < CAP_MBLK) {
    int r = tid << 8;
    int e;
    if (r >= soff[NEXP]) e = NEXP;   // shared expert segment
    else {
      e = 0;
      for (int k = 0; k < NEXP; k++) if (r >= soff[k + 1]) e = k + 1;
      if (e > NEXP - 1) e = NEXP - 1;
    }
    blk_e[tid] = e;
  }
}

// ---------- assign: routed slots + shared segment fill ----------
__global__ void assign_k(const int* topi, const float* topw, int* cursor,
                         const int* meta, int* rowtok, float* rww) {
  int i = blockIdx.x * 256 + threadIdx.x;  // 12288 threads
  if (i < T_TOK * 2) {
    int e = topi[i]; if (e < 0) e = 0; if (e >= NEXP) e = NEXP - 1;
    int r = atomicAdd(&cursor[e], 1);
    if (r < 0) r = 0; if (r >= CAP_ROWS) r = CAP_ROWS - 1;
    rowtok[r] = i >> 1;
    rww[r] = topw[i];
  } else {
    int t = i - T_TOK * 2;            // 0..4095
    int r = meta[1] + t;
    if (r >= CAP_ROWS) r = CAP_ROWS - 1;
    rowtok[r] = t;
    rww[r] = 1.0f;
  }
}

// ---------- transpose+convert, two sources merged on blockIdx.z ----------
// z < zSplit: srcA expert z; z >= zSplit: srcB expert (z - zSplit)
__global__ void transpose_cvt2_k(const float* __restrict__ srcA,
                                 const float* __restrict__ srcB, int zSplit,
                                 u16* __restrict__ dst, int R, int C) {
  __shared__ float tile[32][33];
  int z = blockIdx.z;
  const float* src = (z < zSplit) ? srcA + (size_t)z * R * C
                                  : srcB + (size_t)(z - zSplit) * R * C;
  u16* d = dst + (size_t)z * R * C;
  int c0 = blockIdx.x * 32, r0 = blockIdx.y * 32;
#pragma unroll
  for (int i = 0; i < 4; i++)
    tile[threadIdx.y + i * 8][threadIdx.x] =
        src[(size_t)(r0 + threadIdx.y + i * 8) * C + c0 + threadIdx.x];
  __syncthreads();
#pragma unroll
  for (int i = 0; i < 4; i++)
    d[(size_t)(c0 + threadIdx.y + i * 8) * R + r0 + threadIdx.x] =
        f2b(tile[threadIdx.x][threadIdx.y + i * 8]);
}

// ---------- 256x256 BK=64 8-wave grouped GEMM, static double-buffer ----------
// Fix vs prior round: K-loop manually 2x-unrolled with four SEPARATE __shared__
// arrays so every ds_read / global_load_lds has a compile-time base object ->
// the waitcnt inserter can disambiguate buffers and the explicit counted
// vmcnt(8) is not followed by a compiler vmcnt(0) drain (runtime lds[cur]
// indexing defeated it last round: MfmaUtil 17.6%, drain-per-tile regime).
// MODE 0: gelu -> bf16 store to C16
// MODE 2: atomic f32: Cf[rowtok[row]*N+col] += rww[row]*v  (skip rowtok<0)
template <int MODE>
__global__ __launch_bounds__(512, 2) void gemm256(
    const u16* __restrict__ A, const u16* __restrict__ Bt,
    u16* __restrict__ C16, float* __restrict__ Cf,
    int N, int K, const int* __restrict__ blk_e, const int* __restrict__ meta,
    size_t bstride, const int* __restrict__ gatherA,
    const int* __restrict__ rowtok, const float* __restrict__ rww) {
  // ---- bijective XCD-chunked swizzle of flattened block id (m204 formula) ----
  const int nwg = gridDim.x * gridDim.y;
  const int bid = blockIdx.y * gridDim.x + blockIdx.x;
  const int q = nwg >> 3, r8 = nwg & 7;
  const int xcd = bid & 7, idx = bid >> 3;
  const int swz = (xcd < r8) ? xcd * (q + 1) + idx
                             : r8 * (q + 1) + (xcd - r8) * q + idx;
  const int bx = swz % gridDim.x, by = swz / gridDim.x;

  const int m0 = by * 256, n0 = bx * 256;
  if (m0 >= meta[0]) return;
  Bt += (size_t)blk_e[by] * bstride;

  __shared__ u16 As0[256 * 64];   // 32 KiB each, 128 KiB total
  __shared__ u16 Bs0[256 * 64];
  __shared__ u16 As1[256 * 64];
  __shared__ u16 Bs1[256 * 64];

  const int tid = threadIdx.x;
  const int wave = tid >> 6, lane = tid & 63;
  const int wm = wave >> 2, wn = wave & 3;   // 2 x 4 wave grid
  const int fr = lane & 15, hi = lane >> 4;

  // ---- staging sources: chunk c = i*512+tid covers physical 16B slot (r, c&7)
  // of the [256][64] tile; it fetches LOGICAL slot (c&7)^(r&7)  (XOR swizzle on
  // the global side because global_load_lds writes LDS linearly).
  const u16* asrc[4];
  const u16* bsrc[4];
#pragma unroll
  for (int i = 0; i < 4; i++) {
    int c = i * 512 + tid;
    int r = c >> 3;
    int sl = (c & 7) ^ (r & 7);
    int ga = m0 + r;
    if (gatherA) { int t2 = gatherA[ga]; ga = (t2 < 0 || t2 >= T_TOK) ? 0 : t2; }
    asrc[i] = A + (size_t)ga * K + sl * 8;
    bsrc[i] = Bt + (size_t)(n0 + r) * K + sl * 8;
  }

#define STAGE(kt, AL, BL)                                                      \
  do {                                                                         \
    const int k0_ = (kt) << 6;                                                 \
    _Pragma("unroll")                                                          \
    for (int i_ = 0; i_ < 4; i_++)                                             \
      GLD16(asrc[i_] + k0_, (AL) + i_ * 4096 + wave * 512);                    \
    _Pragma("unroll")                                                          \
    for (int i_ = 0; i_ < 4; i_++)                                             \
      GLD16(bsrc[i_] + k0_, (BL) + i_ * 4096 + wave * 512);                    \
  } while (0)

  // per-lane ds_read col offsets; fragment row r has r&7 == fr&7, so the
  // swizzled slot is a per-(lane,k) constant and fragment addrs are base+imm.
  int co[2];
#pragma unroll
  for (int k = 0; k < 2; k++)
    co[k] = fr * 64 + (((k << 2) + hi) ^ (fr & 7)) * 8;
  const int sA = wm * 8192;   // wm*128 rows * 64
  const int sB = wn * 4096;   // wn*64  rows * 64

  floatx4 acc[8][4];
#pragma unroll
  for (int mi = 0; mi < 8; mi++)
#pragma unroll
    for (int ni = 0; ni < 4; ni++) acc[mi][ni] = (floatx4){0.f, 0.f, 0.f, 0.f};

#define COMPUTE(AL, BL)                                                        \
  do {                                                                         \
    _Pragma("unroll")                                                          \
    for (int ph = 0; ph < 4; ph++) {                                           \
      const int mh = ph >> 1, nh = ph & 1;                                     \
      short8 aF[4][2], bF[2][2];                                               \
      _Pragma("unroll")                                                        \
      for (int mi = 0; mi < 4; mi++)                                           \
        _Pragma("unroll")                                                      \
        for (int k = 0; k < 2; k++)                                            \
          aF[mi][k] =                                                          \
              *(const short8*)((AL) + sA + (mh * 4 + mi) * 1024 + co[k]);      \
      _Pragma("unroll")                                                        \
      for (int ni = 0; ni < 2; ni++)                                           \
        _Pragma("unroll")                                                      \
        for (int k = 0; k < 2; k++)                                            \
          bF[ni][k] =                                                          \
              *(const short8*)((BL) + sB + (nh * 2 + ni) * 1024 + co[k]);      \
      __builtin_amdgcn_s_barrier();                                            \
      __builtin_amdgcn_s_setprio(1);                                           \
      _Pragma("unroll")                                                        \
      for (int mi = 0; mi < 4; mi++)                                           \
        _Pragma("unroll")                                                      \
        for (int ni = 0; ni < 2; ni++)                                         \
          _Pragma("unroll")                                                    \
          for (int k = 0; k < 2; k++)                                          \
            acc[mh * 4 + mi][nh * 2 + ni] =                                    \
                __builtin_amdgcn_mfma_f32_16x16x32_bf16(                       \
                    aF[mi][k], bF[ni][k], acc[mh * 4 + mi][nh * 2 + ni], 0, 0, \
                    0);                                                        \
      __builtin_amdgcn_s_setprio(0);                                           \
      __builtin_amdgcn_s_barrier();                                            \
    }                                                                          \
  } while (0)

  const int NT = K >> 6;  // 16 or 32 here: always even, >= 2
  STAGE(0, As0, Bs0);
  for (int t = 0; t < NT; t += 2) {
    STAGE(t + 1, As1, Bs1);
    asm volatile("s_waitcnt vmcnt(8)" ::: "memory");  // tile t landed; t+1 in flight
    __builtin_amdgcn_s_barrier();
    COMPUTE(As0, Bs0);
    if (t + 2 < NT) {
      STAGE(t + 2, As0, Bs0);
      asm volatile("s_waitcnt vmcnt(8)" ::: "memory");  // tile t+1 landed
    } else {
      asm volatile("s_waitcnt vmcnt(0)" ::: "memory");
    }
    __builtin_amdgcn_s_barrier();
    COMPUTE(As1, Bs1);
  }
#undef STAGE
#undef COMPUTE

  // ---- epilogue: C/D layout col=lane&15, row=(lane>>4)*4+reg ----
#pragma unroll
  for (int mi = 0; mi < 8; mi++)
#pragma unroll
    for (int r = 0; r < 4; r++) {
      int row = m0 + wm * 128 + mi * 16 + hi * 4 + r;
      int tok = 0; float w = 0.f;
      if (MODE == 2) {
        tok = rowtok[row];
        if (tok >= 0) w = rww[row];
      }
#pragma unroll
      for (int ni = 0; ni < 4; ni++) {
        int col = n0 + wn * 64 + ni * 16 + fr;
        float v = acc[mi][ni][r];
        if (MODE == 0) {
          v = 0.5f * v * (1.0f + erff(v * 0.70710678118654752f));
          C16[(size_t)row * N + col] = f2b(v);
        } else {
          if (tok >= 0) atomicAdd(Cf + (size_t)tok * N + col, w * v);
        }
      }
    }
}

extern "C" void kernel_launch(void* const* d_in, const int* in_sizes, int n_in,
                              void* d_out, int out_size, void* d_ws, size_t ws_size,
                              hipStream_t stream) {
  const float* x  = (const float*)d_in[0];
  const float* Wg = (const float*)d_in[1];
  const float* Wu = (const float*)d_in[2];
  const float* Wd = (const float*)d_in[3];
  const float* W1 = (const float*)d_in[4];
  const float* W2 = (const float*)d_in[5];
  float* out = (float*)d_out;

  // ---- workspace layout (~104 MB; Wt reused up->down) ----
  char* ws = (char*)d_ws;
  size_t off = 0;
  auto alloc = [&](size_t b) -> void* {
    void* p = ws + off; off += (b + 255) & ~(size_t)255; return p;
  };
  int*   counts = (int*)alloc(NEXP * 4);
  int*   cursor = (int*)alloc(NEXP * 4);
  int*   meta   = (int*)alloc(2 * 4);
  int*   blk_e  = (int*)alloc(CAP_MBLK * 4);
  int*   topi   = (int*)alloc(T_TOK * 2 * 4);
  float* topw   = (float*)alloc(T_TOK * 2 * 4);
  int*   rowtok = (int*)alloc(CAP_ROWS * 4);
  float* rww    = (float*)alloc(CAP_ROWS * 4);
  u16*   Xb     = (u16*)alloc((size_t)T_TOK * DDIM * 2);                 // 8.4 MB
  u16*   Wt     = (u16*)alloc((size_t)(NEXP + 1) * FDIM * DDIM * 2);     // 37.7 MB
  u16*   Hrg    = (u16*)alloc((size_t)CAP_ROWS * FDIM * 2);              // 57.7 MB
  (void)n_in; (void)in_sizes; (void)out_size;

  if (ws_size < off) {
    fallback_k<<<(T_TOK * DDIM + 255) / 256, 256, 0, stream>>>(out, T_TOK * DDIM);
    return;
  }

  dim3 tb(32, 8);
  // ---- routing (f32 logits: selection must match reference) ----
  prep_k<<<T_TOK * DDIM / 1024, 256, 0, stream>>>(x, Xb, out, counts, rowtok);
  router_k<<<T_TOK / 16, 256, 0, stream>>>(x, Wg, topi, topw, counts);
  scan_k<<<1, 64, 0, stream>>>(counts, cursor, blk_e, meta);
  assign_k<<<(T_TOK * 2 + T_TOK) / 256, 256, 0, stream>>>(topi, topw, cursor, meta,
                                                          rowtok, rww);
  // ---- phase up: Hrg = gelu(gather(x) @ Wu[e])  (expert 8 = shared W1) ----
  transpose_cvt2_k<<<dim3(FDIM / 32, DDIM / 32, NEXP + 1), tb, 0, stream>>>(
      Wu, W1, NEXP, Wt, DDIM, FDIM);
  gemm256<0><<<dim3(FDIM / 256, CAP_MBLK), 512, 0, stream>>>(
      Xb, Wt, Hrg, nullptr, FDIM, DDIM, blk_e, meta, (size_t)FDIM * DDIM,
      rowtok, nullptr, nullptr);
  // ---- phase down: out += rww * (Hrg @ Wd[e])  (expert 8 = shared W2, w=1) ----
  transpose_cvt2_k<<<dim3(DDIM / 32, FDIM / 32, NEXP + 1), tb, 0, stream>>>(
      Wd, W2, NEXP, Wt, FDIM, DDIM);
  gemm256<2><<<dim3(DDIM / 256, CAP_MBLK), 512, 0, stream>>>(
      Hrg, Wt, nullptr, out, DDIM, FDIM, blk_e, meta, (size_t)DDIM * FDIM,
      nullptr, rowtok, rww);
}